// Round 11
// baseline (188.550 us; speedup 1.0000x reference)
//
#include <hip/hip_runtime.h>
#include <stdint.h>

// Round 7: single barrier per tile + counted vmcnt(8) (never-stall: gates
// loads issued one full tile earlier). qf ds_reads issued before softmax so
// their latency hides under the VALU chain. proj/wt unchanged from R6.
//
// ws layout (bytes):
//   VOFF: v  f16, tile-swizzled [256 tiles][64 rows][512B row, 16B-slot swz]  8 MB
//   KOFF: k  f16, same layout                                                  8 MB
//   QOFF: qT f16, per batch [64 tiles][256 c][128B, (c&7)<<4 swizzled]         8 MB
//   WOFF: W^T f16 [3][256 c][256 k]                                            384 KB

typedef _Float16 f16;
typedef __attribute__((ext_vector_type(8))) _Float16 f16x8;
typedef __attribute__((ext_vector_type(4))) float f32x4;
typedef __attribute__((ext_vector_type(4))) unsigned int u32x4;

#define MFMA16(a, b, c) __builtin_amdgcn_mfma_f32_16x16x32_f16((a), (b), (c), 0, 0, 0)

constexpr size_t VOFF = 0;
constexpr size_t KOFF = (size_t)8 << 20;
constexpr size_t QOFF = (size_t)16 << 20;
constexpr size_t WOFF = (size_t)24 << 20;

__device__ inline void gll16(const void* g, void* l) {
  __builtin_amdgcn_global_load_lds(
      (const __attribute__((address_space(1))) uint32_t*)g,
      (__attribute__((address_space(3))) uint32_t*)l, 16, 0, 0);
}

__device__ inline uint32_t pkf16(float a, float b) {
  union { decltype(__builtin_amdgcn_cvt_pkrtz(0.f, 0.f)) h; uint32_t u; } cv;
  cv.h = __builtin_amdgcn_cvt_pkrtz(a, b);
  return cv.u;
}

// ---------------------------------------------------------------- kernel 1
__global__ __launch_bounds__(256) void wt_kernel(const float* __restrict__ wv,
                                                 const float* __restrict__ wk,
                                                 const float* __restrict__ wq,
                                                 f16* __restrict__ wt) {
  int idx = blockIdx.x * 256 + threadIdx.x;
  int p = idx >> 16;
  int rem = idx & 65535;
  int c = rem >> 8, k = rem & 255;
  const float* w = (p == 0) ? wv : (p == 1) ? wk : wq;
  wt[idx] = (f16)w[k * 256 + c];
}

// ---------------------------------------------------------------- kernel 2
// 512 threads, 8 waves: rg=wid&3 (16-row block), ch=wid>>2 (128-col half).
// dynamic LDS: xt 32K | ot 32K | wbuf 64K = 131072 B
__global__ __launch_bounds__(512, 1) void proj_kernel(const float* __restrict__ x,
                                                      uint8_t* __restrict__ ws) {
  extern __shared__ __align__(16) uint8_t plds[];
  uint8_t* xt = plds;
  uint8_t* ot = plds + 32768;
  uint8_t* wbuf = plds + 65536;

  const int tid = threadIdx.x;
  const int blk = blockIdx.x;
  const int lane = tid & 63, wid = tid >> 6;
  const int l15 = lane & 15, g = lane >> 4;
  const int rg = wid & 3, ch = wid >> 2;

  {
    int r = tid >> 3, c0 = (tid & 7) * 32;
    const float* src = x + (size_t)(blk * 64 + r) * 256 + c0;
    int sw = (r & 7) << 4;
#pragma unroll
    for (int j = 0; j < 4; ++j) {
      float4 f0 = *(const float4*)(src + j * 8);
      float4 f1 = *(const float4*)(src + j * 8 + 4);
      f16x8 h;
      h[0] = (f16)f0.x; h[1] = (f16)f0.y; h[2] = (f16)f0.z; h[3] = (f16)f0.w;
      h[4] = (f16)f1.x; h[5] = (f16)f1.y; h[6] = (f16)f1.z; h[7] = (f16)f1.w;
      *(f16x8*)(xt + r * 512 + ((c0 * 2 + j * 16) ^ sw)) = h;
    }
  }
  __syncthreads();

  const uint8_t* wtp = ws + WOFF;
  const int arow = rg * 16 + l15;
  const int asw = (arow & 7) << 4;

  for (int p = 0; p < 3; ++p) {
    f32x4 o[8];
#pragma unroll
    for (int t = 0; t < 8; ++t) o[t] = (f32x4){0.f, 0.f, 0.f, 0.f};

#pragma unroll
    for (int h = 0; h < 2; ++h) {
      __syncthreads();
      const uint8_t* wsrc = wtp + (size_t)p * 131072 + h * 256;
#pragma unroll
      for (int j = 0; j < 8; ++j) {
        int dst = j * 8192 + tid * 16;
        int c = dst >> 8, off = dst & 255;
        gll16(wsrc + c * 512 + (off ^ ((c & 7) << 4)), wbuf + j * 8192 + wid * 1024);
      }
      asm volatile("s_waitcnt vmcnt(0)" ::: "memory");
      __syncthreads();

#pragma unroll
      for (int kc2 = 0; kc2 < 4; ++kc2) {
        int kc = h * 4 + kc2;
        f16x8 a = *(const f16x8*)(xt + arow * 512 + ((kc * 64 + g * 16) ^ asw));
#pragma unroll
        for (int t = 0; t < 8; ++t) {
          int col = ch * 128 + t * 16 + l15;
          f16x8 b = *(const f16x8*)(wbuf + col * 256 +
                                    ((kc2 * 64 + g * 16) ^ ((col & 7) << 4)));
          o[t] = MFMA16(a, b, o[t]);
        }
      }
    }

    __syncthreads();
#pragma unroll
    for (int t = 0; t < 8; ++t) {
#pragma unroll
      for (int r = 0; r < 4; ++r) {
        int prow = rg * 16 + g * 4 + r;
        int pcol = ch * 128 + t * 16 + l15;
        int addr = prow * 512 + ((pcol * 2) ^ ((prow & 7) << 4));
        *(f16*)(ot + addr) = (f16)o[t][r];
      }
    }
    __syncthreads();

    if (p < 2) {
      uint8_t* dst = ws + (p == 0 ? VOFF : KOFF) + (size_t)blk * 32768;
#pragma unroll
      for (int jj = 0; jj < 4; ++jj) {
        u32x4 d = *(const u32x4*)(ot + jj * 8192 + tid * 16);
        *(u32x4*)(dst + jj * 8192 + tid * 16) = d;
      }
    } else {
      int c = tid >> 1, half = tid & 1;
      int b2 = blk >> 6, kt2 = blk & 63;
      uint8_t* dst = ws + QOFF + (size_t)b2 * 2097152 + (size_t)kt2 * 32768 + c * 128;
#pragma unroll
      for (int jj2 = 0; jj2 < 4; ++jj2) {
        int jj = half * 4 + jj2;
        u32x4 d;
#pragma unroll
        for (int q = 0; q < 4; ++q) {
          int r0 = jj * 8 + q * 2, r1 = r0 + 1;
          uint32_t lo = *(const uint16_t*)(ot + r0 * 512 + ((c * 2) ^ ((r0 & 7) << 4)));
          uint32_t hi = *(const uint16_t*)(ot + r1 * 512 + ((c * 2) ^ ((r1 & 7) << 4)));
          d[q] = lo | (hi << 16);
        }
        *(u32x4*)(dst + ((jj * 16) ^ ((c & 7) << 4))) = d;
      }
    }
    __syncthreads();
  }
}

// ---------------------------------------------------------------- kernel 3
// 256 WGs x 512 thr. rg=wid&3 (rows rg*16..+16), kh=wid>>2 (keys kh*32..+32).
// LDS: K dbuf 2*32K @0 | Q dbuf 2*32K @65536 = 131072 B. P lives in registers.
// Per tile: s_barrier -> issue K/Q(t+1) -> vmcnt(8) [K/Q(t) ready, issued one
// full tile earlier -> never stalls] -> ka reads -> QK -> qf reads (hide under
// softmax) -> softmax -> PV.
__global__ __launch_bounds__(512, 2) void flash_kernel(const float* __restrict__ x,
                                                       const float* __restrict__ gptr,
                                                       float* __restrict__ out,
                                                       const uint8_t* __restrict__ ws) {
  extern __shared__ __align__(16) uint8_t lds[];
  const int tid = threadIdx.x, lane = tid & 63, wid = tid >> 6;
  const int l15 = lane & 15, g = lane >> 4;
  const int rg = wid & 3, kh = wid >> 2;

  int blk = blockIdx.x;
  int swz = (blk & 7) * 32 + (blk >> 3);
  int b = swz >> 6, rb = swz & 63;

  const uint8_t* ktile0 = ws + KOFF + (size_t)(b * 64) * 32768;
  const uint8_t* qtile0 = ws + QOFF + (size_t)b * 2097152;

  // V fragments (rows rg*16..+16), registers for the whole kernel (B-operand)
  f16x8 vf[8];
  {
    int r = rg * 16 + l15;
    const uint8_t* vt = ws + VOFF + (size_t)(b * 64 + rb) * 32768 + r * 512;
    int sw = (r & 7) << 4;
#pragma unroll
    for (int cb = 0; cb < 8; ++cb)
      vf[cb] = *(const f16x8*)(vt + ((cb * 64 + g * 16) ^ sw));
  }
  const float gl2 = gptr[0] * 1.44269504088896f;

  // prologue: issue K(0) then Q(0)
#pragma unroll
  for (int i = 0; i < 4; ++i)
    gll16(ktile0 + i * 8192 + tid * 16, lds + i * 8192 + wid * 1024);
#pragma unroll
  for (int i = 0; i < 4; ++i)
    gll16(qtile0 + i * 8192 + tid * 16, lds + 65536 + i * 8192 + wid * 1024);

  f32x4 o[16];
#pragma unroll
  for (int t = 0; t < 16; ++t) o[t] = (f32x4){0.f, 0.f, 0.f, 0.f};
  float m = -1e30f, l = 0.f;  // per-lane: row = l15 (uniform across g)

  const int rbase = (lane & 48) + ((lane & 48) >> 2);  // g*16 + g*4
  const int slo = ((lane >> 4) & 1) * 32 + (lane & 15);
  const int shi = slo + 16;
  const bool thi = (lane & 32) != 0;

  const int key0 = kh * 32 + l15;
  const int ksw = (l15 & 7) << 4;

  for (int kt = 0; kt < 64; ++kt) {
    const int cur = kt & 1;
    const uint8_t* kbuf = lds + cur * 32768;
    const uint8_t* qbuf = lds + 65536 + cur * 32768;

    // ---- single sync point: buf^1 readers done; issue next tile; gate cur ----
    __builtin_amdgcn_sched_barrier(0);
    __builtin_amdgcn_s_barrier();
    __builtin_amdgcn_sched_barrier(0);
    if (kt < 63) {
      const uint8_t* kt1 = ktile0 + (size_t)(kt + 1) * 32768;
      const uint8_t* qt1 = qtile0 + (size_t)(kt + 1) * 32768;
      uint8_t* nk = lds + (cur ^ 1) * 32768;
      uint8_t* nq = lds + 65536 + (cur ^ 1) * 32768;
#pragma unroll
      for (int i = 0; i < 4; ++i)
        gll16(kt1 + i * 8192 + tid * 16, nk + i * 8192 + wid * 1024);
#pragma unroll
      for (int i = 0; i < 4; ++i)
        gll16(qt1 + i * 8192 + tid * 16, nq + i * 8192 + wid * 1024);
      __builtin_amdgcn_sched_barrier(0);
      asm volatile("s_waitcnt vmcnt(8)" ::: "memory");
      __builtin_amdgcn_sched_barrier(0);
    } else {
      __builtin_amdgcn_sched_barrier(0);
      asm volatile("s_waitcnt vmcnt(0)" ::: "memory");
      __builtin_amdgcn_sched_barrier(0);
    }

    // ---- QK: batch-issue 16 ds_reads, then dense MFMA cluster ----
    f16x8 ka[16];
#pragma unroll
    for (int kc = 0; kc < 8; ++kc) {
      ka[kc * 2] = *(const f16x8*)(kbuf + key0 * 512 + ((kc * 64 + g * 16) ^ ksw));
      ka[kc * 2 + 1] =
          *(const f16x8*)(kbuf + (key0 + 16) * 512 + ((kc * 64 + g * 16) ^ ksw));
    }
    __builtin_amdgcn_sched_barrier(0);
    f32x4 s0 = (f32x4){0.f, 0.f, 0.f, 0.f};
    f32x4 s1 = (f32x4){0.f, 0.f, 0.f, 0.f};
    __builtin_amdgcn_s_setprio(1);
#pragma unroll
    for (int kc = 0; kc < 8; ++kc) {
      s0 = MFMA16(ka[kc * 2], vf[kc], s0);
      s1 = MFMA16(ka[kc * 2 + 1], vf[kc], s1);
    }
    __builtin_amdgcn_s_setprio(0);

    // ---- qf reads now: latency hides under the softmax VALU chain ----
    f16x8 qf[16];
#pragma unroll
    for (int t16 = 0; t16 < 16; ++t16) {
      int c = t16 * 16 + l15;
      qf[t16] = *(const f16x8*)(qbuf + c * 128 + ((kh * 64 + g * 16) ^ ((c & 7) << 4)));
    }
    __builtin_amdgcn_sched_barrier(0);

    // ---- softmax: lane owns row l15; keys kh*32 + {t*16 + g*4 + r} ----
    float p[8];
#pragma unroll
    for (int r = 0; r < 4; ++r) {
      p[r] = s0[r] * gl2;
      p[4 + r] = s1[r] * gl2;
    }
    float rm = fmaxf(fmaxf(fmaxf(p[0], p[1]), fmaxf(p[2], p[3])),
                     fmaxf(fmaxf(p[4], p[5]), fmaxf(p[6], p[7])));
    rm = fmaxf(rm, __shfl_xor(rm, 16, 64));
    rm = fmaxf(rm, __shfl_xor(rm, 32, 64));

    if (!__all(rm <= m)) {  // exact defer-max
      float mn = fmaxf(m, rm);
      float sc = __builtin_amdgcn_exp2f(m - mn);
      m = mn;
      l *= sc;
      float sc0 = __shfl(sc, rbase + 0, 64);
      float sc1 = __shfl(sc, rbase + 1, 64);
      float sc2 = __shfl(sc, rbase + 2, 64);
      float sc3 = __shfl(sc, rbase + 3, 64);
#pragma unroll
      for (int t = 0; t < 16; ++t) {
        o[t][0] *= sc0; o[t][1] *= sc1; o[t][2] *= sc2; o[t][3] *= sc3;
      }
    }

    float rs = 0.f;
#pragma unroll
    for (int i = 0; i < 8; ++i) {
      p[i] = __builtin_amdgcn_exp2f(p[i] - m);
      rs += p[i];
    }
    rs += __shfl_xor(rs, 16, 64);
    rs += __shfl_xor(rs, 32, 64);
    l += rs;

    // build PV A-frag in-register
    uint32_t pk00 = pkf16(p[0], p[1]), pk01 = pkf16(p[2], p[3]);
    uint32_t pk10 = pkf16(p[4], p[5]), pk11 = pkf16(p[6], p[7]);
    uint32_t a0l = __shfl(pk00, slo, 64), a0h = __shfl(pk10, slo, 64);
    uint32_t a1l = __shfl(pk01, slo, 64), a1h = __shfl(pk11, slo, 64);
    uint32_t a2l = __shfl(pk00, shi, 64), a2h = __shfl(pk10, shi, 64);
    uint32_t a3l = __shfl(pk01, shi, 64), a3h = __shfl(pk11, shi, 64);
    union { uint32_t u[4]; f16x8 v; } pu;
    pu.u[0] = thi ? a0h : a0l;
    pu.u[1] = thi ? a1h : a1l;
    pu.u[2] = thi ? a2h : a2l;
    pu.u[3] = thi ? a3h : a3l;
    f16x8 pa = pu.v;

    // ---- PV: O(16x256) += P(16x32) @ Q_half(32x256), all-register ----
    __builtin_amdgcn_s_setprio(1);
#pragma unroll
    for (int t16 = 0; t16 < 16; ++t16) o[t16] = MFMA16(pa, qf[t16], o[t16]);
    __builtin_amdgcn_s_setprio(0);
  }

  __syncthreads();  // loop done (no glls outstanding); LDS free for merge

  // ---- merge kh=1 partials into kh=0, write out ----
  if (kh == 1) {
    uint8_t* ob = lds + rg * 16384;
#pragma unroll
    for (int t16 = 0; t16 < 16; ++t16) *(f32x4*)(ob + t16 * 1024 + lane * 16) = o[t16];
    if (g == 0) {
      uint8_t* mlb = lds + 65536 + rg * 128;
      *(float*)(mlb + l15 * 8) = m;
      *(float*)(mlb + l15 * 8 + 4) = l;
    }
  }
  __syncthreads();
  if (kh == 0) {
    const uint8_t* ob = lds + rg * 16384;
    const uint8_t* mlb = lds + 65536 + rg * 128;
    float pm = *(const float*)(mlb + l15 * 8);
    float pl = *(const float*)(mlb + l15 * 8 + 4);
    float mn = fmaxf(m, pm);
    float a = __builtin_amdgcn_exp2f(m - mn);
    float bs = __builtin_amdgcn_exp2f(pm - mn);
    float inv = 1.0f / (l * a + pl * bs);
    float ar[4], br[4], ir[4];
#pragma unroll
    for (int r = 0; r < 4; ++r) {
      ar[r] = __shfl(a, rbase + r, 64);
      br[r] = __shfl(bs, rbase + r, 64);
      ir[r] = __shfl(inv, rbase + r, 64);
    }
#pragma unroll
    for (int t16 = 0; t16 < 16; ++t16) {
      f32x4 po = *(const f32x4*)(ob + t16 * 1024 + lane * 16);
#pragma unroll
      for (int r = 0; r < 4; ++r) {
        size_t grow = (size_t)b * 4096 + (size_t)rb * 64 + rg * 16 + g * 4 + r;
        size_t idx = grow * 256 + t16 * 16 + l15;
        out[idx] = (o[t16][r] * ar[r] + po[r] * br[r]) * ir[r] + x[idx];
      }
    }
  }
}

// ---------------------------------------------------------------- launch
extern "C" void kernel_launch(void* const* d_in, const int* in_sizes, int n_in,
                              void* d_out, int out_size, void* d_ws, size_t ws_size,
                              hipStream_t stream) {
  (void)in_sizes; (void)n_in; (void)out_size; (void)ws_size;
  const float* x = (const float*)d_in[0];
  const float* wv = (const float*)d_in[1];
  const float* wk = (const float*)d_in[2];
  const float* wq = (const float*)d_in[3];
  const float* gamma = (const float*)d_in[4];
  float* out = (float*)d_out;
  uint8_t* ws = (uint8_t*)d_ws;

  wt_kernel<<<768, 256, 0, stream>>>(wv, wk, wq, (f16*)(ws + WOFF));

  (void)hipFuncSetAttribute((const void*)proj_kernel,
                            hipFuncAttributeMaxDynamicSharedMemorySize, 131072);
  proj_kernel<<<256, 512, 131072, stream>>>(x, ws);

  (void)hipFuncSetAttribute((const void*)flash_kernel,
                            hipFuncAttributeMaxDynamicSharedMemorySize, 131072);
  flash_kernel<<<256, 512, 131072, stream>>>(x, gamma, out, ws);
}

// Round 12
// 140.380 us; speedup vs baseline: 1.3431x; 1.3431x over previous
//
#include <hip/hip_runtime.h>
#include <stdint.h>

// Round 12: 32x32x16 MFMA flash (halves LDS traffic), key-split quarters
// (512 WGs x 256thr, 2 WG/CU, independent barriers), K/Q dbuf via
// global_load_lds with R6-correct sync order (issue -> vmcnt(10) -> barrier),
// conflict-free K swizzle (row&31)<<4, Q image padded to 72B rows (2-way max),
// in-register P via cvt_pkrtz + shfl_xor(32). f16 partials + merge kernel.
//
// ws layout (bytes), total ~58.5 MB:
//   WOFF  0        : W^T f16 [3][256 c][256 k]                     384 KB
//   VOFF  0.5 MB   : v f16 [b*64+rb][64 rows][512B], (row&31)<<4   8 MB
//   KOFF  8.5 MB   : k f16 same layout                              8 MB
//   QOFF  16.5 MB  : qT f16 [b][kt 0..127][256 c][72B (64 data+8)]  9 MB
//   MLOFF ~25.9 MB : (m,l) f32 pairs [16 bq][4096 n]                512 KB
//   POFF  ~26.4 MB : partial O f16 [16 bq][4096 n][256 c]           32 MB

typedef _Float16 f16;
typedef __attribute__((ext_vector_type(8))) _Float16 f16x8;
typedef __attribute__((ext_vector_type(4))) float f32x4;
typedef __attribute__((ext_vector_type(16))) float f32x16;
typedef __attribute__((ext_vector_type(4))) unsigned int u32x4;

#define MFMA16(a, b, c) __builtin_amdgcn_mfma_f32_16x16x32_f16((a), (b), (c), 0, 0, 0)
#define MFMA32(a, b, c) __builtin_amdgcn_mfma_f32_32x32x16_f16((a), (b), (c), 0, 0, 0)

constexpr size_t WOFF = 0;
constexpr size_t VOFF = (size_t)1 << 19;            // 524288
constexpr size_t KOFF = VOFF + ((size_t)8 << 20);
constexpr size_t QOFF = KOFF + ((size_t)8 << 20);
constexpr size_t QSZ = (size_t)4 * 128 * 256 * 72;  // 9437184
constexpr size_t MLOFF = QOFF + QSZ;
constexpr size_t POFF = MLOFF + (size_t)16 * 4096 * 8;

__device__ inline void gll16(const void* g, void* l) {
  __builtin_amdgcn_global_load_lds(
      (const __attribute__((address_space(1))) uint32_t*)g,
      (__attribute__((address_space(3))) uint32_t*)l, 16, 0, 0);
}
__device__ inline void gll4(const void* g, void* l) {
  __builtin_amdgcn_global_load_lds(
      (const __attribute__((address_space(1))) uint32_t*)g,
      (__attribute__((address_space(3))) uint32_t*)l, 4, 0, 0);
}

__device__ inline uint32_t pkf16(float a, float b) {
  union { decltype(__builtin_amdgcn_cvt_pkrtz(0.f, 0.f)) h; uint32_t u; } cv;
  cv.h = __builtin_amdgcn_cvt_pkrtz(a, b);
  return cv.u;
}

// ---------------------------------------------------------------- kernel 1
__global__ __launch_bounds__(256) void wt_kernel(const float* __restrict__ wv,
                                                 const float* __restrict__ wk,
                                                 const float* __restrict__ wq,
                                                 f16* __restrict__ wt) {
  int idx = blockIdx.x * 256 + threadIdx.x;
  int p = idx >> 16;
  int rem = idx & 65535;
  int c = rem >> 8, k = rem & 255;
  const float* w = (p == 0) ? wv : (p == 1) ? wk : wq;
  wt[idx] = (f16)w[k * 256 + c];
}

// ---------------------------------------------------------------- kernel 2
// 512 threads, 8 waves: rg=wid&3 (16-row block), ch=wid>>2 (128-col half).
// dynamic LDS: xt 32K | ot 32K | wbuf 64K = 131072 B
__global__ __launch_bounds__(512, 1) void proj_kernel(const float* __restrict__ x,
                                                      uint8_t* __restrict__ ws) {
  extern __shared__ __align__(16) uint8_t plds[];
  uint8_t* xt = plds;
  uint8_t* ot = plds + 32768;
  uint8_t* wbuf = plds + 65536;

  const int tid = threadIdx.x;
  const int blk = blockIdx.x;
  const int lane = tid & 63, wid = tid >> 6;
  const int l15 = lane & 15, g = lane >> 4;
  const int rg = wid & 3, ch = wid >> 2;

  {
    int r = tid >> 3, c0 = (tid & 7) * 32;
    const float* src = x + (size_t)(blk * 64 + r) * 256 + c0;
    int sw = (r & 7) << 4;
#pragma unroll
    for (int j = 0; j < 4; ++j) {
      float4 f0 = *(const float4*)(src + j * 8);
      float4 f1 = *(const float4*)(src + j * 8 + 4);
      f16x8 h;
      h[0] = (f16)f0.x; h[1] = (f16)f0.y; h[2] = (f16)f0.z; h[3] = (f16)f0.w;
      h[4] = (f16)f1.x; h[5] = (f16)f1.y; h[6] = (f16)f1.z; h[7] = (f16)f1.w;
      *(f16x8*)(xt + r * 512 + ((c0 * 2 + j * 16) ^ sw)) = h;
    }
  }
  __syncthreads();

  const uint8_t* wtp = ws + WOFF;
  const int arow = rg * 16 + l15;
  const int asw = (arow & 7) << 4;

  for (int p = 0; p < 3; ++p) {
    f32x4 o[8];
#pragma unroll
    for (int t = 0; t < 8; ++t) o[t] = (f32x4){0.f, 0.f, 0.f, 0.f};

#pragma unroll
    for (int h = 0; h < 2; ++h) {
      __syncthreads();
      const uint8_t* wsrc = wtp + (size_t)p * 131072 + h * 256;
#pragma unroll
      for (int j = 0; j < 8; ++j) {
        int dst = j * 8192 + tid * 16;
        int c = dst >> 8, off = dst & 255;
        gll16(wsrc + c * 512 + (off ^ ((c & 7) << 4)), wbuf + j * 8192 + wid * 1024);
      }
      asm volatile("s_waitcnt vmcnt(0)" ::: "memory");
      __syncthreads();

#pragma unroll
      for (int kc2 = 0; kc2 < 4; ++kc2) {
        int kc = h * 4 + kc2;
        f16x8 a = *(const f16x8*)(xt + arow * 512 + ((kc * 64 + g * 16) ^ asw));
#pragma unroll
        for (int t = 0; t < 8; ++t) {
          int col = ch * 128 + t * 16 + l15;
          f16x8 b = *(const f16x8*)(wbuf + col * 256 +
                                    ((kc2 * 64 + g * 16) ^ ((col & 7) << 4)));
          o[t] = MFMA16(a, b, o[t]);
        }
      }
    }

    __syncthreads();
    // frags -> ot (f16, row-swizzled with (row&31)<<4 to match flash readers)
#pragma unroll
    for (int t = 0; t < 8; ++t) {
#pragma unroll
      for (int r = 0; r < 4; ++r) {
        int prow = rg * 16 + g * 4 + r;
        int pcol = ch * 128 + t * 16 + l15;
        int addr = prow * 512 + ((pcol * 2) ^ ((prow & 31) << 4));
        *(f16*)(ot + addr) = (f16)o[t][r];
      }
    }
    __syncthreads();

    if (p < 2) {
      uint8_t* dst = ws + (p == 0 ? VOFF : KOFF) + (size_t)blk * 32768;
#pragma unroll
      for (int jj = 0; jj < 4; ++jj) {
        u32x4 d = *(const u32x4*)(ot + jj * 8192 + tid * 16);
        *(u32x4*)(dst + jj * 8192 + tid * 16) = d;
      }
    } else {
      // Q image: [b][kt][c][72B]: key k (0..31) at byte k*2; 8B-aligned stores
      int c = tid & 255, t = tid >> 8;  // t in 0..1
      int b2 = blk >> 6;
      int kt2 = (blk & 63) * 2 + t;
      uint8_t* dst = ws + QOFF + ((size_t)b2 * 128 + kt2) * 18432 + (size_t)c * 72;
#pragma unroll
      for (int kk = 0; kk < 8; ++kk) {
        union { uint16_t u[4]; uint64_t v; } d;
#pragma unroll
        for (int q = 0; q < 4; ++q) {
          int k = kk * 4 + q;
          int r = t * 32 + k;
          d.u[q] = *(const uint16_t*)(ot + r * 512 + ((c * 2) ^ ((r & 31) << 4)));
        }
        *(uint64_t*)(dst + kk * 8) = d.v;
      }
    }
    __syncthreads();
  }
}

// ---------------------------------------------------------------- kernel 3
// 512 WGs x 256 thr (2 WG/CU). WG = (b, qtr, rb): rows rb*128..+128, keys
// qtr*1024..+1024 in 32 tiles of 32. 4 waves = 4 row-groups of 32 rows.
// LDS: K dbuf 2*16K @0 | Q dbuf 2*18432 @32768 = 69632 B.
// Per tile: s_barrier -> issue K/Q(t+1) -> vmcnt(10) -> s_barrier -> compute.
__global__ __launch_bounds__(256, 2) void flash_kernel(const float* __restrict__ gptr,
                                                       uint8_t* __restrict__ ws) {
  extern __shared__ __align__(16) uint8_t lds[];
  const int tid = threadIdx.x, lane = tid & 63, wid = tid >> 6;
  const int l31 = lane & 31, hi = lane >> 5;
  const int rg = wid;

  // XCD-aware decode: blk%8 = XCD; each (b,qtr) group of 32 rb-WGs on one XCD
  int blk = blockIdx.x;
  int c8 = blk & 7, i = blk >> 3;
  int g16 = c8 * 2 + (i >> 5);
  int rb = i & 31;
  int b = g16 >> 2, qtr = g16 & 3;
  const int n0 = rb * 128 + rg * 32;  // wave's first row (within batch)

  // V fragments (32 rows x 256 c), registers for whole kernel (B-operand)
  f16x8 vf[16];
  {
    int gn = b * 4096 + n0 + l31;
    const uint8_t* vrow = ws + VOFF + (size_t)gn * 512;
    int sw = (gn & 31) << 4;
#pragma unroll
    for (int kc = 0; kc < 16; ++kc)
      vf[kc] = *(const f16x8*)(vrow + ((kc * 32 + hi * 16) ^ sw));
  }
  const float gl2 = gptr[0] * 1.44269504088896f;

  const uint8_t* kbase = ws + KOFF + ((size_t)(b * 4096 + qtr * 1024)) * 512;
  const uint8_t* qbase = ws + QOFF + ((size_t)b * 128 + qtr * 32) * 18432;

  // prologue: issue tile 0 (10 glls; all waves uniform)
  {
    uint8_t* kd = lds;
    uint8_t* qd = lds + 32768;
#pragma unroll
    for (int ii = 0; ii < 4; ++ii) gll16(kbase + ii * 4096 + tid * 16, kd + ii * 4096 + wid * 1024);
#pragma unroll
    for (int ii = 0; ii < 4; ++ii) gll16(qbase + ii * 4096 + tid * 16, qd + ii * 4096 + wid * 1024);
#pragma unroll
    for (int j = 0; j < 2; ++j)
      gll4(qbase + 16384 + j * 1024 + tid * 4, qd + 16384 + j * 1024 + wid * 256);
  }

  f32x16 o[8];
#pragma unroll
  for (int cf = 0; cf < 8; ++cf)
#pragma unroll
    for (int j = 0; j < 16; ++j) o[cf][j] = 0.f;
  float m = -1e30f, lsum = 0.f;  // per lane: row n0 + (lane&31)

  for (int t = 0; t < 32; ++t) {
    const int cur = t & 1;
    uint8_t* kb = lds + cur * 16384;
    uint8_t* qb = lds + 32768 + cur * 18432;

    __builtin_amdgcn_sched_barrier(0);
    __builtin_amdgcn_s_barrier();  // all waves done reading buf cur^1
    __builtin_amdgcn_sched_barrier(0);
    if (t < 31) {  // issue tile t+1 into buf cur^1, then drain OWN tile-t glls
      const uint8_t* ks = kbase + (size_t)(t + 1) * 16384;
      const uint8_t* qs = qbase + (size_t)(t + 1) * 18432;
      uint8_t* kd = lds + (cur ^ 1) * 16384;
      uint8_t* qd = lds + 32768 + (cur ^ 1) * 18432;
#pragma unroll
      for (int ii = 0; ii < 4; ++ii) gll16(ks + ii * 4096 + tid * 16, kd + ii * 4096 + wid * 1024);
#pragma unroll
      for (int ii = 0; ii < 4; ++ii) gll16(qs + ii * 4096 + tid * 16, qd + ii * 4096 + wid * 1024);
#pragma unroll
      for (int j = 0; j < 2; ++j)
        gll4(qs + 16384 + j * 1024 + tid * 4, qd + 16384 + j * 1024 + wid * 256);
      __builtin_amdgcn_sched_barrier(0);
      asm volatile("s_waitcnt vmcnt(10)" ::: "memory");
    } else {
      __builtin_amdgcn_sched_barrier(0);
      asm volatile("s_waitcnt vmcnt(0)" ::: "memory");
    }
    __builtin_amdgcn_s_barrier();  // ALL waves' tile-t glls have landed
    __builtin_amdgcn_sched_barrier(0);

    // ---- QK: S^T(32 keys x 32 rows) = K_tile @ V^T, 16 x mfma 32x32x16 ----
    f32x16 s;
#pragma unroll
    for (int j = 0; j < 16; ++j) s[j] = 0.f;
    const int ksw = l31 << 4;
    __builtin_amdgcn_s_setprio(1);
#pragma unroll
    for (int kc = 0; kc < 16; ++kc) {
      f16x8 ka = *(const f16x8*)(kb + l31 * 512 + ((kc * 32 + hi * 16) ^ ksw));
      s = MFMA32(ka, vf[kc], s);
    }
    __builtin_amdgcn_s_setprio(0);

    // ---- softmax: lane owns row n0+l31; 16 keys in regs, partner has rest --
    float p[16];
    float rm = -1e30f;
#pragma unroll
    for (int j = 0; j < 16; ++j) {
      p[j] = s[j] * gl2;
      rm = fmaxf(rm, p[j]);
    }
    rm = fmaxf(rm, __shfl_xor(rm, 32, 64));

    if (!__all(rm <= m)) {  // exact defer-max
      float mn = fmaxf(m, rm);
      float sc = __builtin_amdgcn_exp2f(m - mn);
      m = mn;
      lsum *= sc;
      float scr[16];
#pragma unroll
      for (int j = 0; j < 16; ++j)
        scr[j] = __shfl(sc, (j & 3) + 8 * (j >> 2) + 4 * hi, 64);
#pragma unroll
      for (int cf = 0; cf < 8; ++cf)
#pragma unroll
        for (int j = 0; j < 16; ++j) o[cf][j] *= scr[j];
    }

    float rs = 0.f;
#pragma unroll
    for (int j = 0; j < 16; ++j) {
      p[j] = __builtin_amdgcn_exp2f(p[j] - m);
      rs += p[j];
    }
    rs += __shfl_xor(rs, 32, 64);
    lsum += rs;

    // ---- pack P -> PV A-frags (keys: (j&3)+8*(j>>2)+4*hi per reg j) ----
    uint32_t w[8], sw[8];
#pragma unroll
    for (int ii = 0; ii < 8; ++ii) w[ii] = pkf16(p[2 * ii], p[2 * ii + 1]);
#pragma unroll
    for (int ii = 0; ii < 8; ++ii) sw[ii] = __shfl_xor(w[ii], 32, 64);
    union { uint32_t u[4]; f16x8 v; } A1, A2;
    A1.u[0] = hi ? sw[2] : w[0];
    A1.u[1] = hi ? sw[3] : w[1];
    A1.u[2] = hi ? w[2] : sw[0];
    A1.u[3] = hi ? w[3] : sw[1];
    A2.u[0] = hi ? sw[6] : w[4];
    A2.u[1] = hi ? sw[7] : w[5];
    A2.u[2] = hi ? w[6] : sw[4];
    A2.u[3] = hi ? w[7] : sw[5];

    // ---- PV: O(32 x 256) += P(32 x 32) @ Q(32 keys x 256 c) ----
    __builtin_amdgcn_s_setprio(1);
#pragma unroll
    for (int cf = 0; cf < 8; ++cf) {
      const uint8_t* qp = qb + (size_t)(cf * 32 + l31) * 72 + hi * 16;
      union { uint64_t u[2]; f16x8 v; } q1, q2;
      q1.u[0] = *(const uint64_t*)(qp);
      q1.u[1] = *(const uint64_t*)(qp + 8);
      q2.u[0] = *(const uint64_t*)(qp + 32);
      q2.u[1] = *(const uint64_t*)(qp + 40);
      o[cf] = MFMA32(A1.v, q1.v, o[cf]);
      o[cf] = MFMA32(A2.v, q2.v, o[cf]);
    }
    __builtin_amdgcn_s_setprio(0);
  }

  // ---- epilogue: write (m,l) + unnormalized partial O (f16) ----
  const int bq = b * 4 + qtr;
  if (lane < 32) {
    float2 ml2;
    ml2.x = m;
    ml2.y = lsum;
    *(float2*)(ws + MLOFF + ((size_t)bq * 4096 + n0 + lane) * 8) = ml2;
  }
#pragma unroll
  for (int cf = 0; cf < 8; ++cf) {
#pragma unroll
    for (int j = 0; j < 16; ++j) {
      int row = (j & 3) + 8 * (j >> 2) + 4 * hi;
      size_t n = (size_t)bq * 4096 + n0 + row;
      *(f16*)(ws + POFF + (n * 256 + cf * 32 + l31) * 2) = (f16)o[cf][j];
    }
  }
}

// ---------------------------------------------------------------- kernel 4
// merge 4 quarter-partials per row: out = (sum Oq e^{mq-M}) / (sum lq e^{mq-M}) + x
__global__ __launch_bounds__(256) void merge_kernel(const float* __restrict__ x,
                                                    float* __restrict__ out,
                                                    const uint8_t* __restrict__ ws) {
  int gn = blockIdx.x;  // 0..16383 = b*4096 + n
  int b = gn >> 12, n = gn & 4095;
  int c = threadIdx.x;

  float mq[4], lq[4];
#pragma unroll
  for (int q = 0; q < 4; ++q) {
    const float2 ml = *(const float2*)(ws + MLOFF + ((size_t)(b * 4 + q) * 4096 + n) * 8);
    mq[q] = ml.x;
    lq[q] = ml.y;
  }
  float M = fmaxf(fmaxf(mq[0], mq[1]), fmaxf(mq[2], mq[3]));
  float eq[4], L = 0.f;
#pragma unroll
  for (int q = 0; q < 4; ++q) {
    eq[q] = __builtin_amdgcn_exp2f(mq[q] - M);
    L += lq[q] * eq[q];
  }
  float acc = 0.f;
#pragma unroll
  for (int q = 0; q < 4; ++q) {
    float pv = (float)*(const f16*)(ws + POFF +
                                    (((size_t)(b * 4 + q) * 4096 + n) * 256 + c) * 2);
    acc += pv * eq[q];
  }
  size_t idx = (size_t)gn * 256 + c;
  out[idx] = acc / L + x[idx];
}

// ---------------------------------------------------------------- launch
extern "C" void kernel_launch(void* const* d_in, const int* in_sizes, int n_in,
                              void* d_out, int out_size, void* d_ws, size_t ws_size,
                              hipStream_t stream) {
  (void)in_sizes; (void)n_in; (void)out_size; (void)ws_size;
  const float* x = (const float*)d_in[0];
  const float* wv = (const float*)d_in[1];
  const float* wk = (const float*)d_in[2];
  const float* wq = (const float*)d_in[3];
  const float* gamma = (const float*)d_in[4];
  float* out = (float*)d_out;
  uint8_t* ws = (uint8_t*)d_ws;

  wt_kernel<<<768, 256, 0, stream>>>(wv, wk, wq, (f16*)(ws + WOFF));

  (void)hipFuncSetAttribute((const void*)proj_kernel,
                            hipFuncAttributeMaxDynamicSharedMemorySize, 131072);
  proj_kernel<<<256, 512, 131072, stream>>>(x, ws);

  (void)hipFuncSetAttribute((const void*)flash_kernel,
                            hipFuncAttributeMaxDynamicSharedMemorySize, 69632);
  flash_kernel<<<512, 256, 69632, stream>>>(gamma, ws);

  merge_kernel<<<16384, 256, 0, stream>>>(x, out, ws);
}